// Round 4
// baseline (6534.366 us; speedup 1.0000x reference)
//
#include <hip/hip_runtime.h>
#include <hip/hip_bf16.h>

#define SEQ 4096
#define HID 2048
#define HK_ 16
#define HV_ 32
#define KEY_DIM 2048
#define VALUE_DIM 4096
#define CONV_DIM 8192
#define NQKVZ 12288

typedef unsigned short ushort_t;

__device__ __forceinline__ float bf2f(ushort_t h) {
    union { unsigned int u; float f; } x; x.u = ((unsigned int)h) << 16; return x.f;
}
__device__ __forceinline__ void cvt8(uint4 v, float* f) {
    unsigned int w[4] = {v.x, v.y, v.z, v.w};
#pragma unroll
    for (int i = 0; i < 4; i++) {
        union { unsigned int u; float f; } lo, hi;
        lo.u = w[i] << 16; hi.u = w[i] & 0xffff0000u;
        f[2 * i] = lo.f; f[2 * i + 1] = hi.f;
    }
}
__device__ __forceinline__ ushort_t f2bf(float f) {
    union { float f; unsigned int u; } x; x.f = f;
    unsigned int u = x.u;
    u += 0x7fffu + ((u >> 16) & 1u);   // round-to-nearest-even
    return (ushort_t)(u >> 16);
}

// ---------------------------------------------------------------------------
// ba = hidden @ W_ba (2048x64), f32 in, fused g/beta transform, f32 out.
// BM=128, BN=64, BK=16, 256 threads, 8x4 per thread. grid = 32 blocks.
// ---------------------------------------------------------------------------
__global__ void k_ba(const float* __restrict__ A, const float* __restrict__ B,
                     const float* __restrict__ A_log, const float* __restrict__ dt_bias,
                     float* __restrict__ egb, float* __restrict__ betab)
{
    __shared__ float As[16][132];
    __shared__ float Bs[16][68];
    int tid = threadIdx.x;
    int m0 = blockIdx.x * 128;
    int tx = tid & 15, ty = tid >> 4;
    int arow = tid >> 2, akq = tid & 3;
    int brow = tid >> 4, bc4 = tid & 15;
    float acc[8][4];
#pragma unroll
    for (int i = 0; i < 8; i++)
#pragma unroll
        for (int j = 0; j < 4; j++) acc[i][j] = 0.f;

    for (int k0 = 0; k0 < HID; k0 += 16) {
        float4 a0 = *(const float4*)&A[(size_t)(m0 + arow) * HID + k0 + akq * 4];
        float4 a1 = *(const float4*)&A[(size_t)(m0 + arow + 64) * HID + k0 + akq * 4];
        float4 b0 = *(const float4*)&B[(size_t)(k0 + brow) * 64 + bc4 * 4];
        __syncthreads();
        As[akq * 4 + 0][arow] = a0.x; As[akq * 4 + 1][arow] = a0.y;
        As[akq * 4 + 2][arow] = a0.z; As[akq * 4 + 3][arow] = a0.w;
        As[akq * 4 + 0][arow + 64] = a1.x; As[akq * 4 + 1][arow + 64] = a1.y;
        As[akq * 4 + 2][arow + 64] = a1.z; As[akq * 4 + 3][arow + 64] = a1.w;
        *(float4*)&Bs[brow][bc4 * 4] = b0;
        __syncthreads();
#pragma unroll
        for (int kk = 0; kk < 16; kk++) {
            float xa[8], yb[4];
            *(float4*)&xa[0] = *(const float4*)&As[kk][ty * 8];
            *(float4*)&xa[4] = *(const float4*)&As[kk][ty * 8 + 4];
            *(float4*)&yb[0] = *(const float4*)&Bs[kk][tx * 4];
#pragma unroll
            for (int i = 0; i < 8; i++)
#pragma unroll
                for (int j = 0; j < 4; j++) acc[i][j] += xa[i] * yb[j];
        }
    }
#pragma unroll
    for (int i = 0; i < 8; i++) {
        int t = m0 + ty * 8 + i;
#pragma unroll
        for (int j = 0; j < 4; j++) {
            int c = tx * 4 + j;
            int hk = c >> 2, rr = c & 3;
            float val = acc[i][j];
            if (rr < 2) {
                int hv = hk * 2 + rr;
                betab[t * HV_ + hv] = 1.f / (1.f + expf(-val));
            } else {
                int hv = hk * 2 + (rr - 2);
                float v2 = val + dt_bias[hv];
                float sp = (v2 > 20.f) ? v2 : log1pf(expf(v2));
                float g = -expf(A_log[hv]) * sp;
                egb[t * HV_ + hv] = expf(g);
            }
        }
    }
}

// ---------------------------------------------------------------------------
// qkvz = hidden @ W_qkvz (2048x12288), f32 in, bf16 out with column remap.
// BM=128, BN=128, BK=16, 256 threads, 8x8 per thread. grid = (96, 32).
// ---------------------------------------------------------------------------
__global__ void k_gemm_qkvz(const float* __restrict__ A, const float* __restrict__ B,
                            ushort_t* __restrict__ preact, ushort_t* __restrict__ zb)
{
    __shared__ float As[16][132];
    __shared__ float Bs[16][132];
    int tid = threadIdx.x;
    int m0 = blockIdx.y * 128, n0 = blockIdx.x * 128;
    int tx = tid & 15, ty = tid >> 4;
    int arow = tid >> 2, akq = tid & 3;
    int brow = tid >> 5, bc4 = tid & 31;
    float acc[8][8];
#pragma unroll
    for (int i = 0; i < 8; i++)
#pragma unroll
        for (int j = 0; j < 8; j++) acc[i][j] = 0.f;

    for (int k0 = 0; k0 < HID; k0 += 16) {
        float4 a0 = *(const float4*)&A[(size_t)(m0 + arow) * HID + k0 + akq * 4];
        float4 a1 = *(const float4*)&A[(size_t)(m0 + arow + 64) * HID + k0 + akq * 4];
        float4 b0 = *(const float4*)&B[(size_t)(k0 + brow) * NQKVZ + n0 + bc4 * 4];
        float4 b1 = *(const float4*)&B[(size_t)(k0 + brow + 8) * NQKVZ + n0 + bc4 * 4];
        __syncthreads();
        As[akq * 4 + 0][arow] = a0.x; As[akq * 4 + 1][arow] = a0.y;
        As[akq * 4 + 2][arow] = a0.z; As[akq * 4 + 3][arow] = a0.w;
        As[akq * 4 + 0][arow + 64] = a1.x; As[akq * 4 + 1][arow + 64] = a1.y;
        As[akq * 4 + 2][arow + 64] = a1.z; As[akq * 4 + 3][arow + 64] = a1.w;
        *(float4*)&Bs[brow][bc4 * 4] = b0;
        *(float4*)&Bs[brow + 8][bc4 * 4] = b1;
        __syncthreads();
#pragma unroll
        for (int kk = 0; kk < 16; kk++) {
            float xa[8], yb[8];
            *(float4*)&xa[0] = *(const float4*)&As[kk][ty * 8];
            *(float4*)&xa[4] = *(const float4*)&As[kk][ty * 8 + 4];
            *(float4*)&yb[0] = *(const float4*)&Bs[kk][tx * 8];
            *(float4*)&yb[4] = *(const float4*)&Bs[kk][tx * 8 + 4];
#pragma unroll
            for (int i = 0; i < 8; i++)
#pragma unroll
                for (int j = 0; j < 8; j++) acc[i][j] += xa[i] * yb[j];
        }
    }
    // remap: block col j = hk*768 + r ; r<128 q | r<256 k | r<512 v | else z
    int hk = n0 / 768, r = n0 % 768;
    ushort_t* dst; int ldd;
    if (r < 128)      { dst = preact + hk * 128;                   ldd = CONV_DIM; }
    else if (r < 256) { dst = preact + 2048 + hk * 128;            ldd = CONV_DIM; }
    else if (r < 512) { dst = preact + 4096 + hk * 256 + (r - 256); ldd = CONV_DIM; }
    else              { dst = zb + hk * 256 + (r - 512);           ldd = VALUE_DIM; }
#pragma unroll
    for (int i = 0; i < 8; i++) {
        int m = m0 + ty * 8 + i;
        ushort_t us[8];
#pragma unroll
        for (int j = 0; j < 8; j++) us[j] = f2bf(acc[i][j]);
        *(uint4*)&dst[(size_t)m * ldd + tx * 8] = *(uint4*)us;
    }
}

// ---------------------------------------------------------------------------
// Causal conv(K=4) + SiLU; l2norm for q/k heads. Block=128 threads handles
// one 128-channel slot for 4 consecutive timesteps. grid = (64, 1024).
// ---------------------------------------------------------------------------
__global__ void k_conv(const ushort_t* __restrict__ pre, const float* __restrict__ cw,
                       ushort_t* __restrict__ qn, ushort_t* __restrict__ kn,
                       ushort_t* __restrict__ vv)
{
    __shared__ float red[4][2];
    int s = blockIdx.x;
    int t0 = blockIdx.y * 4;
    int d = threadIdx.x;
    int c = s * 128 + d;
    float w[4];
    *(float4*)w = *(const float4*)&cw[(size_t)c * 4];
    float p[7];
#pragma unroll
    for (int i = 0; i < 7; i++) {
        int tt = t0 + i - 3;
        p[i] = (tt >= 0) ? bf2f(pre[(size_t)tt * CONV_DIM + c]) : 0.f;
    }
    float x[4];
#pragma unroll
    for (int u = 0; u < 4; u++) {
        float a = p[u] * w[0] + p[u + 1] * w[1] + p[u + 2] * w[2] + p[u + 3] * w[3];
        x[u] = a / (1.f + expf(-a));
    }
    if (s < 32) {
        int wv = d >> 6, ln = d & 63;
#pragma unroll
        for (int u = 0; u < 4; u++) {
            float ss = x[u] * x[u];
            for (int m = 32; m >= 1; m >>= 1) ss += __shfl_xor(ss, m, 64);
            if (ln == 0) red[u][wv] = ss;
        }
        __syncthreads();
#pragma unroll
        for (int u = 0; u < 4; u++) {
            float tot = red[u][0] + red[u][1];
            float scale = 1.f / sqrtf(tot + 1e-6f);
            float val = x[u] * scale;
            int t = t0 + u;
            if (s < 16) qn[(size_t)t * KEY_DIM + s * 128 + d] = f2bf(val * 0.08838834764831845f);
            else        kn[(size_t)t * KEY_DIM + (s - 16) * 128 + d] = f2bf(val);
        }
    } else {
#pragma unroll
        for (int u = 0; u < 4; u++)
            vv[(size_t)(t0 + u) * VALUE_DIM + (s - 32) * 128 + d] = f2bf(x[u]);
    }
}

// ---------------------------------------------------------------------------
// Gated delta recurrence. Columns of S along DV are independent:
// one column per 16 consecutive lanes (each lane holds 8 k-elements of S).
// grid = (8 col-blocks of 16, 32 heads), block = 256.
// ---------------------------------------------------------------------------
__global__ void k_recur(const ushort_t* __restrict__ qn, const ushort_t* __restrict__ kn,
                        const ushort_t* __restrict__ vv, const float* __restrict__ eg,
                        const float* __restrict__ betab, float* __restrict__ core)
{
    int h = blockIdx.y;
    int hk = h >> 1;
    int kc = threadIdx.x & 15;        // k-chunk (8 elems each)
    int cl = threadIdx.x >> 4;        // column within block
    int col = blockIdx.x * 16 + cl;
    int kqoff = hk * 128 + kc * 8;

    float S[8];
#pragma unroll
    for (int j = 0; j < 8; j++) S[j] = 0.f;

    float ck[8], cq[8], cv, ce, cb;
    cvt8(*(const uint4*)&kn[kqoff], ck);
    cvt8(*(const uint4*)&qn[kqoff], cq);
    cv = bf2f(vv[h * 128 + col]);
    ce = eg[h];
    cb = betab[h];

    for (int t = 0; t < SEQ; t++) {
        int tn = (t + 1 < SEQ) ? t + 1 : t;
        float nk[8], nq[8], nv, ne, nb;
        cvt8(*(const uint4*)&kn[(size_t)tn * KEY_DIM + kqoff], nk);
        cvt8(*(const uint4*)&qn[(size_t)tn * KEY_DIM + kqoff], nq);
        nv = bf2f(vv[(size_t)tn * VALUE_DIM + h * 128 + col]);
        ne = eg[tn * HV_ + h];
        nb = betab[tn * HV_ + h];

        float pq = 0.f;
#pragma unroll
        for (int j = 0; j < 8; j++) { S[j] *= ce; pq += S[j] * ck[j]; }
        pq += __shfl_xor(pq, 1, 16);
        pq += __shfl_xor(pq, 2, 16);
        pq += __shfl_xor(pq, 4, 16);
        pq += __shfl_xor(pq, 8, 16);
        float dl = (cv - pq) * cb;
        float o = 0.f;
#pragma unroll
        for (int j = 0; j < 8; j++) { S[j] += ck[j] * dl; o += S[j] * cq[j]; }
        o += __shfl_xor(o, 1, 16);
        o += __shfl_xor(o, 2, 16);
        o += __shfl_xor(o, 4, 16);
        o += __shfl_xor(o, 8, 16);
        if (kc == 0) core[(size_t)t * VALUE_DIM + h * 128 + col] = o;

#pragma unroll
        for (int j = 0; j < 8; j++) { ck[j] = nk[j]; cq[j] = nq[j]; }
        cv = nv; ce = ne; cb = nb;
    }
}

// ---------------------------------------------------------------------------
// RMS norm over DV + norm_weight + silu(z) gate, in place on core (f32).
// grid = (32, 4096), block = 128.
// ---------------------------------------------------------------------------
__global__ void k_gate(float* __restrict__ core, const ushort_t* __restrict__ z,
                       const float* __restrict__ nw)
{
    __shared__ float red[2];
    int hv = blockIdx.x, t = blockIdx.y, d = threadIdx.x;
    size_t idx = (size_t)t * VALUE_DIM + hv * 128 + d;
    float cval = core[idx];
    float ss = cval * cval;
    for (int m = 32; m >= 1; m >>= 1) ss += __shfl_xor(ss, m, 64);
    int wv = d >> 6, ln = d & 63;
    if (ln == 0) red[wv] = ss;
    __syncthreads();
    float var = (red[0] + red[1]) * (1.f / 128.f);
    float zv = bf2f(z[idx]);
    float out = cval * (1.f / sqrtf(var + 1e-6f)) * nw[d] * (zv / (1.f + expf(-zv)));
    core[idx] = out;
}

// ---------------------------------------------------------------------------
// out = core (4096x4096, f32 ws) @ W_out (4096x2048, f32) -> f32 out.
// grid = (16, 32).
// ---------------------------------------------------------------------------
__global__ void k_gemm_out(const float* __restrict__ A, const float* __restrict__ B,
                           float* __restrict__ C)
{
    __shared__ float As[16][132];
    __shared__ float Bs[16][132];
    int tid = threadIdx.x;
    int m0 = blockIdx.y * 128, n0 = blockIdx.x * 128;
    int tx = tid & 15, ty = tid >> 4;
    int arow = tid >> 2, akq = tid & 3;
    int brow = tid >> 5, bc4 = tid & 31;
    float acc[8][8];
#pragma unroll
    for (int i = 0; i < 8; i++)
#pragma unroll
        for (int j = 0; j < 8; j++) acc[i][j] = 0.f;

    for (int k0 = 0; k0 < VALUE_DIM; k0 += 16) {
        float4 a0 = *(const float4*)&A[(size_t)(m0 + arow) * VALUE_DIM + k0 + akq * 4];
        float4 a1 = *(const float4*)&A[(size_t)(m0 + arow + 64) * VALUE_DIM + k0 + akq * 4];
        float4 b0 = *(const float4*)&B[(size_t)(k0 + brow) * HID + n0 + bc4 * 4];
        float4 b1 = *(const float4*)&B[(size_t)(k0 + brow + 8) * HID + n0 + bc4 * 4];
        __syncthreads();
        As[akq * 4 + 0][arow] = a0.x; As[akq * 4 + 1][arow] = a0.y;
        As[akq * 4 + 2][arow] = a0.z; As[akq * 4 + 3][arow] = a0.w;
        As[akq * 4 + 0][arow + 64] = a1.x; As[akq * 4 + 1][arow + 64] = a1.y;
        As[akq * 4 + 2][arow + 64] = a1.z; As[akq * 4 + 3][arow + 64] = a1.w;
        *(float4*)&Bs[brow][bc4 * 4] = b0;
        *(float4*)&Bs[brow + 8][bc4 * 4] = b1;
        __syncthreads();
#pragma unroll
        for (int kk = 0; kk < 16; kk++) {
            float xa[8], yb[8];
            *(float4*)&xa[0] = *(const float4*)&As[kk][ty * 8];
            *(float4*)&xa[4] = *(const float4*)&As[kk][ty * 8 + 4];
            *(float4*)&yb[0] = *(const float4*)&Bs[kk][tx * 8];
            *(float4*)&yb[4] = *(const float4*)&Bs[kk][tx * 8 + 4];
#pragma unroll
            for (int i = 0; i < 8; i++)
#pragma unroll
                for (int j = 0; j < 8; j++) acc[i][j] += xa[i] * yb[j];
        }
    }
#pragma unroll
    for (int i = 0; i < 8; i++) {
        int m = m0 + ty * 8 + i;
        float4 v0, v1;
        v0.x = acc[i][0]; v0.y = acc[i][1]; v0.z = acc[i][2]; v0.w = acc[i][3];
        v1.x = acc[i][4]; v1.y = acc[i][5]; v1.z = acc[i][6]; v1.w = acc[i][7];
        *(float4*)&C[(size_t)m * HID + n0 + tx * 8]     = v0;
        *(float4*)&C[(size_t)m * HID + n0 + tx * 8 + 4] = v1;
    }
}

// ---------------------------------------------------------------------------
// Workspace layout (bytes), total 168,820,736 (~161 MB):
//   [0, 64M)    preact bf16 (SEQ*CONV_DIM)  -- reused as core f32 (SEQ*VALUE_DIM*4)
//   [64M, 96M)  z bf16
//   [96M, ..]   eg f32, beta f32, qn bf16, kn bf16, vv bf16
// Round-3 evidence: this footprint passed the guard (kernels ran), so
// ws_size >= 161 MB. Round-1's 385 MB aborted -> keep ws well under that.
// ---------------------------------------------------------------------------
extern "C" void kernel_launch(void* const* d_in, const int* in_sizes, int n_in,
                              void* d_out, int out_size, void* d_ws, size_t ws_size,
                              hipStream_t stream)
{
    const float* hs    = (const float*)d_in[0];
    const float* Wqkvz = (const float*)d_in[1];
    const float* Wba   = (const float*)d_in[2];
    const float* convw = (const float*)d_in[3];
    const float* Alog  = (const float*)d_in[4];
    const float* dtb   = (const float*)d_in[5];
    const float* nw    = (const float*)d_in[6];
    const float* Wout  = (const float*)d_in[7];
    float* out = (float*)d_out;

    char* w = (char*)d_ws;
    ushort_t* preact = (ushort_t*)w;            // 64 MB (bf16)
    float*    coreb  = (float*)w;               // aliases preact (dead after k_conv)
    w += (size_t)SEQ * CONV_DIM * 2;
    ushort_t* zb = (ushort_t*)w;  w += (size_t)SEQ * VALUE_DIM * 2;
    float* egb   = (float*)w;     w += (size_t)SEQ * HV_ * 4;
    float* betab = (float*)w;     w += (size_t)SEQ * HV_ * 4;
    ushort_t* qnb = (ushort_t*)w; w += (size_t)SEQ * KEY_DIM * 2;
    ushort_t* knb = (ushort_t*)w; w += (size_t)SEQ * KEY_DIM * 2;
    ushort_t* vvb = (ushort_t*)w; w += (size_t)SEQ * VALUE_DIM * 2;
    size_t needed = (size_t)(w - (char*)d_ws);
    if (ws_size < needed) return;   // constant per-session: graph-safe; clean diagnosable failure

    hipLaunchKernelGGL(k_ba, dim3(32), dim3(256), 0, stream, hs, Wba, Alog, dtb, egb, betab);
    hipLaunchKernelGGL(k_gemm_qkvz, dim3(96, 32), dim3(256), 0, stream, hs, Wqkvz, preact, zb);
    hipLaunchKernelGGL(k_conv, dim3(64, 1024), dim3(128), 0, stream, preact, convw, qnb, knb, vvb);
    hipLaunchKernelGGL(k_recur, dim3(8, 32), dim3(256), 0, stream, qnb, knb, vvb, egb, betab, coreb);
    hipLaunchKernelGGL(k_gate, dim3(32, 4096), dim3(128), 0, stream, coreb, zb, nw);
    hipLaunchKernelGGL(k_gemm_out, dim3(16, 32), dim3(256), 0, stream, coreb, Wout, out);
}

// Round 5
// 3736.326 us; speedup vs baseline: 1.7489x; 1.7489x over previous
//
#include <hip/hip_runtime.h>
#include <hip/hip_bf16.h>

#define SEQ 4096
#define HID 2048
#define HK_ 16
#define HV_ 32
#define KEY_DIM 2048
#define VALUE_DIM 4096
#define CONV_DIM 8192
#define NQKVZ 12288

typedef unsigned short ushort_t;
typedef short bf16x8 __attribute__((ext_vector_type(8)));
typedef float f32x4 __attribute__((ext_vector_type(4)));

__device__ __forceinline__ float bf2f(ushort_t h) {
    union { unsigned int u; float f; } x; x.u = ((unsigned int)h) << 16; return x.f;
}
__device__ __forceinline__ void cvt8(uint4 v, float* f) {
    unsigned int w[4] = {v.x, v.y, v.z, v.w};
#pragma unroll
    for (int i = 0; i < 4; i++) {
        union { unsigned int u; float f; } lo, hi;
        lo.u = w[i] << 16; hi.u = w[i] & 0xffff0000u;
        f[2 * i] = lo.f; f[2 * i + 1] = hi.f;
    }
}
__device__ __forceinline__ ushort_t f2bf(float f) {
    union { float f; unsigned int u; } x; x.f = f;
    unsigned int u = x.u;
    u += 0x7fffu + ((u >> 16) & 1u);   // round-to-nearest-even
    return (ushort_t)(u >> 16);
}

// ---------------------------------------------------------------------------
// f32 -> bf16 flat copy (n divisible by 2048). 8 elems/thread.
// ---------------------------------------------------------------------------
__global__ void k_cvt(const float* __restrict__ src, ushort_t* __restrict__ dst)
{
    size_t i = ((size_t)blockIdx.x * 256 + threadIdx.x) * 8;
    float4 a = *(const float4*)&src[i];
    float4 b = *(const float4*)&src[i + 4];
    ushort_t u[8];
    u[0]=f2bf(a.x); u[1]=f2bf(a.y); u[2]=f2bf(a.z); u[3]=f2bf(a.w);
    u[4]=f2bf(b.x); u[5]=f2bf(b.y); u[6]=f2bf(b.z); u[7]=f2bf(b.w);
    *(uint4*)&dst[i] = *(uint4*)u;
}

// ---------------------------------------------------------------------------
// Transpose f32 [R][C] -> bf16 [C][R]. 64x64 tiles via LDS. grid (C/64, R/64).
// ---------------------------------------------------------------------------
__global__ __launch_bounds__(256) void k_transpose(const float* __restrict__ src,
                                                   ushort_t* __restrict__ dst,
                                                   int R, int C)
{
    __shared__ float tile[64][65];
    int c0 = blockIdx.x * 64, r0 = blockIdx.y * 64;
    int t = threadIdx.x;
    int tr = t >> 4, tc = (t & 15) * 4;
#pragma unroll
    for (int r = 0; r < 4; r++) {
        float4 v = *(const float4*)&src[(size_t)(r0 + tr + r * 16) * C + c0 + tc];
        tile[tr + r * 16][tc + 0] = v.x;
        tile[tr + r * 16][tc + 1] = v.y;
        tile[tr + r * 16][tc + 2] = v.z;
        tile[tr + r * 16][tc + 3] = v.w;
    }
    __syncthreads();
#pragma unroll
    for (int r = 0; r < 4; r++) {
        int n = c0 + tr + r * 16;           // dst row (src col)
        ushort_t u[4];
#pragma unroll
        for (int i = 0; i < 4; i++) u[i] = f2bf(tile[tc + i][tr + r * 16]);
        *(uint2*)&dst[(size_t)n * R + r0 + tc] = *(uint2*)u;
    }
}

// ---------------------------------------------------------------------------
// ba = hidden @ W_ba (2048x64), f32 in, fused g/beta transform, f32 out.
// ---------------------------------------------------------------------------
__global__ void k_ba(const float* __restrict__ A, const float* __restrict__ B,
                     const float* __restrict__ A_log, const float* __restrict__ dt_bias,
                     float* __restrict__ egb, float* __restrict__ betab)
{
    __shared__ float As[16][132];
    __shared__ float Bs[16][68];
    int tid = threadIdx.x;
    int m0 = blockIdx.x * 128;
    int tx = tid & 15, ty = tid >> 4;
    int arow = tid >> 2, akq = tid & 3;
    int brow = tid >> 4, bc4 = tid & 15;
    float acc[8][4];
#pragma unroll
    for (int i = 0; i < 8; i++)
#pragma unroll
        for (int j = 0; j < 4; j++) acc[i][j] = 0.f;

    for (int k0 = 0; k0 < HID; k0 += 16) {
        float4 a0 = *(const float4*)&A[(size_t)(m0 + arow) * HID + k0 + akq * 4];
        float4 a1 = *(const float4*)&A[(size_t)(m0 + arow + 64) * HID + k0 + akq * 4];
        float4 b0 = *(const float4*)&B[(size_t)(k0 + brow) * 64 + bc4 * 4];
        __syncthreads();
        As[akq * 4 + 0][arow] = a0.x; As[akq * 4 + 1][arow] = a0.y;
        As[akq * 4 + 2][arow] = a0.z; As[akq * 4 + 3][arow] = a0.w;
        As[akq * 4 + 0][arow + 64] = a1.x; As[akq * 4 + 1][arow + 64] = a1.y;
        As[akq * 4 + 2][arow + 64] = a1.z; As[akq * 4 + 3][arow + 64] = a1.w;
        *(float4*)&Bs[brow][bc4 * 4] = b0;
        __syncthreads();
#pragma unroll
        for (int kk = 0; kk < 16; kk++) {
            float xa[8], yb[4];
            *(float4*)&xa[0] = *(const float4*)&As[kk][ty * 8];
            *(float4*)&xa[4] = *(const float4*)&As[kk][ty * 8 + 4];
            *(float4*)&yb[0] = *(const float4*)&Bs[kk][tx * 4];
#pragma unroll
            for (int i = 0; i < 8; i++)
#pragma unroll
                for (int j = 0; j < 4; j++) acc[i][j] += xa[i] * yb[j];
        }
    }
#pragma unroll
    for (int i = 0; i < 8; i++) {
        int t = m0 + ty * 8 + i;
#pragma unroll
        for (int j = 0; j < 4; j++) {
            int c = tx * 4 + j;
            int hk = c >> 2, rr = c & 3;
            float val = acc[i][j];
            if (rr < 2) {
                int hv = hk * 2 + rr;
                betab[t * HV_ + hv] = 1.f / (1.f + expf(-val));
            } else {
                int hv = hk * 2 + (rr - 2);
                float v2 = val + dt_bias[hv];
                float sp = (v2 > 20.f) ? v2 : log1pf(expf(v2));
                float g = -expf(A_log[hv]) * sp;
                egb[t * HV_ + hv] = expf(g);
            }
        }
    }
}

// ---------------------------------------------------------------------------
// MFMA GEMM: qkvz = hs_bf16 [4096][2048] @ WqkvzT_bf16 [12288][2048]^T.
// 128x128 tile, BK=32, 4 waves (64x64 each, 4x4 mfma frags). grid (96, 32).
// C/D layout (m89-verified): col = lane&15, row = (lane>>4)*4 + reg.
// A/B operand: [row = lane&15][k = (lane>>4)*8 + j], j=0..7.
// ---------------------------------------------------------------------------
__global__ __launch_bounds__(256) void k_gemm_qkvz(const ushort_t* __restrict__ Ab,
                                                   const ushort_t* __restrict__ Bt,
                                                   ushort_t* __restrict__ preact,
                                                   ushort_t* __restrict__ zb)
{
    __shared__ ushort_t As[128][40];   // pitch 80B: 16B-aligned rows, conflict-optimal
    __shared__ ushort_t Bs[128][40];
    int tid = threadIdx.x;
    int m0 = blockIdx.y * 128, n0 = blockIdx.x * 128;
    int lane = tid & 63, wave = tid >> 6;
    int wm = (wave >> 1) * 64, wn = (wave & 1) * 64;
    int quad = lane >> 4, l16 = lane & 15;
    int sr = tid >> 1, sh = tid & 1;    // staging: row 0..127, k-half 0/1

    f32x4 acc[4][4];
#pragma unroll
    for (int i = 0; i < 4; i++)
#pragma unroll
        for (int j = 0; j < 4; j++) acc[i][j] = (f32x4){0.f, 0.f, 0.f, 0.f};

    for (int k0 = 0; k0 < HID; k0 += 32) {
        uint4 av0 = *(const uint4*)&Ab[(size_t)(m0 + sr) * HID + k0 + sh * 16];
        uint4 av1 = *(const uint4*)&Ab[(size_t)(m0 + sr) * HID + k0 + sh * 16 + 8];
        uint4 bv0 = *(const uint4*)&Bt[(size_t)(n0 + sr) * HID + k0 + sh * 16];
        uint4 bv1 = *(const uint4*)&Bt[(size_t)(n0 + sr) * HID + k0 + sh * 16 + 8];
        __syncthreads();
        *(uint4*)&As[sr][sh * 16]     = av0;
        *(uint4*)&As[sr][sh * 16 + 8] = av1;
        *(uint4*)&Bs[sr][sh * 16]     = bv0;
        *(uint4*)&Bs[sr][sh * 16 + 8] = bv1;
        __syncthreads();
        bf16x8 af[4], bfr[4];
#pragma unroll
        for (int i = 0; i < 4; i++) af[i]  = *(bf16x8*)&As[wm + i * 16 + l16][quad * 8];
#pragma unroll
        for (int j = 0; j < 4; j++) bfr[j] = *(bf16x8*)&Bs[wn + j * 16 + l16][quad * 8];
#pragma unroll
        for (int i = 0; i < 4; i++)
#pragma unroll
            for (int j = 0; j < 4; j++)
                acc[i][j] = __builtin_amdgcn_mfma_f32_16x16x32_bf16(af[i], bfr[j], acc[i][j], 0, 0, 0);
    }
    // remap: block col group n0 = hk*768 + r ; r<128 q | <256 k | <512 v | else z
    int hk = n0 / 768, r = n0 % 768;
    ushort_t* dst; int ldd;
    if (r < 128)      { dst = preact + hk * 128;                    ldd = CONV_DIM; }
    else if (r < 256) { dst = preact + 2048 + hk * 128;             ldd = CONV_DIM; }
    else if (r < 512) { dst = preact + 4096 + hk * 256 + (r - 256); ldd = CONV_DIM; }
    else              { dst = zb + hk * 256 + (r - 512);            ldd = VALUE_DIM; }
#pragma unroll
    for (int i = 0; i < 4; i++)
#pragma unroll
        for (int j = 0; j < 4; j++)
#pragma unroll
            for (int rg = 0; rg < 4; rg++) {
                int m = m0 + wm + i * 16 + quad * 4 + rg;
                int n = wn + j * 16 + l16;
                dst[(size_t)m * ldd + n] = f2bf(acc[i][j][rg]);
            }
}

// ---------------------------------------------------------------------------
// MFMA GEMM: out = core_bf16 [4096][4096] @ WoutT_bf16 [2048][4096]^T -> f32.
// Same structure. grid (16, 32).
// ---------------------------------------------------------------------------
__global__ __launch_bounds__(256) void k_gemm_out(const ushort_t* __restrict__ Ab,
                                                  const ushort_t* __restrict__ Bt,
                                                  float* __restrict__ C)
{
    __shared__ ushort_t As[128][40];
    __shared__ ushort_t Bs[128][40];
    int tid = threadIdx.x;
    int m0 = blockIdx.y * 128, n0 = blockIdx.x * 128;
    int lane = tid & 63, wave = tid >> 6;
    int wm = (wave >> 1) * 64, wn = (wave & 1) * 64;
    int quad = lane >> 4, l16 = lane & 15;
    int sr = tid >> 1, sh = tid & 1;

    f32x4 acc[4][4];
#pragma unroll
    for (int i = 0; i < 4; i++)
#pragma unroll
        for (int j = 0; j < 4; j++) acc[i][j] = (f32x4){0.f, 0.f, 0.f, 0.f};

    for (int k0 = 0; k0 < VALUE_DIM; k0 += 32) {
        uint4 av0 = *(const uint4*)&Ab[(size_t)(m0 + sr) * VALUE_DIM + k0 + sh * 16];
        uint4 av1 = *(const uint4*)&Ab[(size_t)(m0 + sr) * VALUE_DIM + k0 + sh * 16 + 8];
        uint4 bv0 = *(const uint4*)&Bt[(size_t)(n0 + sr) * VALUE_DIM + k0 + sh * 16];
        uint4 bv1 = *(const uint4*)&Bt[(size_t)(n0 + sr) * VALUE_DIM + k0 + sh * 16 + 8];
        __syncthreads();
        *(uint4*)&As[sr][sh * 16]     = av0;
        *(uint4*)&As[sr][sh * 16 + 8] = av1;
        *(uint4*)&Bs[sr][sh * 16]     = bv0;
        *(uint4*)&Bs[sr][sh * 16 + 8] = bv1;
        __syncthreads();
        bf16x8 af[4], bfr[4];
#pragma unroll
        for (int i = 0; i < 4; i++) af[i]  = *(bf16x8*)&As[wm + i * 16 + l16][quad * 8];
#pragma unroll
        for (int j = 0; j < 4; j++) bfr[j] = *(bf16x8*)&Bs[wn + j * 16 + l16][quad * 8];
#pragma unroll
        for (int i = 0; i < 4; i++)
#pragma unroll
            for (int j = 0; j < 4; j++)
                acc[i][j] = __builtin_amdgcn_mfma_f32_16x16x32_bf16(af[i], bfr[j], acc[i][j], 0, 0, 0);
    }
#pragma unroll
    for (int i = 0; i < 4; i++)
#pragma unroll
        for (int j = 0; j < 4; j++)
#pragma unroll
            for (int rg = 0; rg < 4; rg++) {
                int m = m0 + wm + i * 16 + quad * 4 + rg;
                int n = n0 + wn + j * 16 + l16;
                C[(size_t)m * HID + n] = acc[i][j][rg];
            }
}

// ---------------------------------------------------------------------------
// Causal conv(K=4) + SiLU; l2norm for q/k heads. grid = (64, 1024).
// ---------------------------------------------------------------------------
__global__ void k_conv(const ushort_t* __restrict__ pre, const float* __restrict__ cw,
                       ushort_t* __restrict__ qn, ushort_t* __restrict__ kn,
                       ushort_t* __restrict__ vv)
{
    __shared__ float red[4][2];
    int s = blockIdx.x;
    int t0 = blockIdx.y * 4;
    int d = threadIdx.x;
    int c = s * 128 + d;
    float w[4];
    *(float4*)w = *(const float4*)&cw[(size_t)c * 4];
    float p[7];
#pragma unroll
    for (int i = 0; i < 7; i++) {
        int tt = t0 + i - 3;
        p[i] = (tt >= 0) ? bf2f(pre[(size_t)tt * CONV_DIM + c]) : 0.f;
    }
    float x[4];
#pragma unroll
    for (int u = 0; u < 4; u++) {
        float a = p[u] * w[0] + p[u + 1] * w[1] + p[u + 2] * w[2] + p[u + 3] * w[3];
        x[u] = a / (1.f + expf(-a));
    }
    if (s < 32) {
        int wv = d >> 6, ln = d & 63;
#pragma unroll
        for (int u = 0; u < 4; u++) {
            float ss = x[u] * x[u];
            for (int m = 32; m >= 1; m >>= 1) ss += __shfl_xor(ss, m, 64);
            if (ln == 0) red[u][wv] = ss;
        }
        __syncthreads();
#pragma unroll
        for (int u = 0; u < 4; u++) {
            float tot = red[u][0] + red[u][1];
            float scale = 1.f / sqrtf(tot + 1e-6f);
            float val = x[u] * scale;
            int t = t0 + u;
            if (s < 16) qn[(size_t)t * KEY_DIM + s * 128 + d] = f2bf(val * 0.08838834764831845f);
            else        kn[(size_t)t * KEY_DIM + (s - 16) * 128 + d] = f2bf(val);
        }
    } else {
#pragma unroll
        for (int u = 0; u < 4; u++)
            vv[(size_t)(t0 + u) * VALUE_DIM + (s - 32) * 128 + d] = f2bf(x[u]);
    }
}

// ---------------------------------------------------------------------------
// Gated delta recurrence (unchanged). grid = (8, 32), block = 256.
// ---------------------------------------------------------------------------
__global__ void k_recur(const ushort_t* __restrict__ qn, const ushort_t* __restrict__ kn,
                        const ushort_t* __restrict__ vv, const float* __restrict__ eg,
                        const float* __restrict__ betab, float* __restrict__ core)
{
    int h = blockIdx.y;
    int hk = h >> 1;
    int kc = threadIdx.x & 15;
    int cl = threadIdx.x >> 4;
    int col = blockIdx.x * 16 + cl;
    int kqoff = hk * 128 + kc * 8;

    float S[8];
#pragma unroll
    for (int j = 0; j < 8; j++) S[j] = 0.f;

    float ck[8], cq[8], cv, ce, cb;
    cvt8(*(const uint4*)&kn[kqoff], ck);
    cvt8(*(const uint4*)&qn[kqoff], cq);
    cv = bf2f(vv[h * 128 + col]);
    ce = eg[h];
    cb = betab[h];

    for (int t = 0; t < SEQ; t++) {
        int tn = (t + 1 < SEQ) ? t + 1 : t;
        float nk[8], nq[8], nv, ne, nb;
        cvt8(*(const uint4*)&kn[(size_t)tn * KEY_DIM + kqoff], nk);
        cvt8(*(const uint4*)&qn[(size_t)tn * KEY_DIM + kqoff], nq);
        nv = bf2f(vv[(size_t)tn * VALUE_DIM + h * 128 + col]);
        ne = eg[tn * HV_ + h];
        nb = betab[tn * HV_ + h];

        float pq = 0.f;
#pragma unroll
        for (int j = 0; j < 8; j++) { S[j] *= ce; pq += S[j] * ck[j]; }
        pq += __shfl_xor(pq, 1, 16);
        pq += __shfl_xor(pq, 2, 16);
        pq += __shfl_xor(pq, 4, 16);
        pq += __shfl_xor(pq, 8, 16);
        float dl = (cv - pq) * cb;
        float o = 0.f;
#pragma unroll
        for (int j = 0; j < 8; j++) { S[j] += ck[j] * dl; o += S[j] * cq[j]; }
        o += __shfl_xor(o, 1, 16);
        o += __shfl_xor(o, 2, 16);
        o += __shfl_xor(o, 4, 16);
        o += __shfl_xor(o, 8, 16);
        if (kc == 0) core[(size_t)t * VALUE_DIM + h * 128 + col] = o;

#pragma unroll
        for (int j = 0; j < 8; j++) { ck[j] = nk[j]; cq[j] = nq[j]; }
        cv = nv; ce = ne; cb = nb;
    }
}

// ---------------------------------------------------------------------------
// RMS norm + gate; emits bf16 core for the MFMA out-GEMM. grid (32,4096).
// ---------------------------------------------------------------------------
__global__ void k_gate(const float* __restrict__ core, const ushort_t* __restrict__ z,
                       const float* __restrict__ nw, ushort_t* __restrict__ corebf)
{
    __shared__ float red[2];
    int hv = blockIdx.x, t = blockIdx.y, d = threadIdx.x;
    size_t idx = (size_t)t * VALUE_DIM + hv * 128 + d;
    float cval = core[idx];
    float ss = cval * cval;
    for (int m = 32; m >= 1; m >>= 1) ss += __shfl_xor(ss, m, 64);
    int wv = d >> 6, ln = d & 63;
    if (ln == 0) red[wv] = ss;
    __syncthreads();
    float var = (red[0] + red[1]) * (1.f / 128.f);
    float zv = bf2f(z[idx]);
    float out = cval * (1.f / sqrtf(var + 1e-6f)) * nw[d] * (zv / (1.f + expf(-zv)));
    corebf[idx] = f2bf(out);
}

// ---------------------------------------------------------------------------
// Workspace (161 MB, proven to fit in round 4):
//   P [0,64M):   preact bf16 -> core f32 (after conv)
//   Z [64,96M):  z bf16
//   eg, beta (1 MB)
//   QKV [97,161M): qn/kn/vv bf16 (64 MB contiguous)
// Aliases by lifetime:
//   before conv: QKV holds WqkvzT bf16 (48 MB) + hs bf16 (16 MB)
//   after recur: vv holds WoutT bf16 (16 MB); qn+kn hold core_bf16 (32 MB)
// ---------------------------------------------------------------------------
extern "C" void kernel_launch(void* const* d_in, const int* in_sizes, int n_in,
                              void* d_out, int out_size, void* d_ws, size_t ws_size,
                              hipStream_t stream)
{
    const float* hs    = (const float*)d_in[0];
    const float* Wqkvz = (const float*)d_in[1];
    const float* Wba   = (const float*)d_in[2];
    const float* convw = (const float*)d_in[3];
    const float* Alog  = (const float*)d_in[4];
    const float* dtb   = (const float*)d_in[5];
    const float* nw    = (const float*)d_in[6];
    const float* Wout  = (const float*)d_in[7];
    float* out = (float*)d_out;

    char* w = (char*)d_ws;
    ushort_t* preact = (ushort_t*)w;            // 64 MB (bf16)
    float*    coreb  = (float*)w;               // aliases preact (dead after k_conv)
    w += (size_t)SEQ * CONV_DIM * 2;
    ushort_t* zb = (ushort_t*)w;  w += (size_t)SEQ * VALUE_DIM * 2;
    float* egb   = (float*)w;     w += (size_t)SEQ * HV_ * 4;
    float* betab = (float*)w;     w += (size_t)SEQ * HV_ * 4;
    ushort_t* qnb = (ushort_t*)w; w += (size_t)SEQ * KEY_DIM * 2;
    ushort_t* knb = (ushort_t*)w; w += (size_t)SEQ * KEY_DIM * 2;
    ushort_t* vvb = (ushort_t*)w; w += (size_t)SEQ * VALUE_DIM * 2;
    size_t needed = (size_t)(w - (char*)d_ws);
    if (ws_size < needed) return;

    // lifetime aliases
    ushort_t* wqT    = qnb;                               // 48 MB: [12288][2048] bf16
    ushort_t* hsb    = qnb + (size_t)24 * 1024 * 1024;    // 16 MB: [4096][2048] bf16
    ushort_t* woutT  = vvb;                               // 16 MB: [2048][4096] bf16
    ushort_t* corebf = qnb;                               // 32 MB: [4096][4096] bf16

    hipLaunchKernelGGL(k_ba, dim3(32), dim3(256), 0, stream, hs, Wba, Alog, dtb, egb, betab);
    hipLaunchKernelGGL(k_cvt, dim3(4096), dim3(256), 0, stream, hs, hsb);
    hipLaunchKernelGGL(k_transpose, dim3(192, 32), dim3(256), 0, stream, Wqkvz, wqT, HID, NQKVZ);
    hipLaunchKernelGGL(k_gemm_qkvz, dim3(96, 32), dim3(256), 0, stream, hsb, wqT, preact, zb);
    hipLaunchKernelGGL(k_conv, dim3(64, 1024), dim3(128), 0, stream, preact, convw, qnb, knb, vvb);
    hipLaunchKernelGGL(k_recur, dim3(8, 32), dim3(256), 0, stream, qnb, knb, vvb, egb, betab, coreb);
    hipLaunchKernelGGL(k_transpose, dim3(32, 64), dim3(256), 0, stream, Wout, woutT, VALUE_DIM, HID);
    hipLaunchKernelGGL(k_gate, dim3(32, 4096), dim3(128), 0, stream, coreb, zb, nw, corebf);
    hipLaunchKernelGGL(k_gemm_out, dim3(16, 32), dim3(256), 0, stream, corebf, woutT, out);
}